// Round 1
// baseline (898.115 us; speedup 1.0000x reference)
//
#include <hip/hip_runtime.h>
#include <math.h>

// Problem constants (from reference): B=2048, L=64, E=256, U=512
#define BATCH 2048
#define LDIM 64
#define EDIM 256
#define UDIM 512

// Fused Bahdanau attention.
// One block per batch element b. 256 threads = 4 waves.
//   tx = tid&31  -> column group (4 consecutive U-columns per chunk)
//   ty = tid>>5  -> row group (8 L-rows)
// LDS: features[b] 64x256 fp32 = 64 KB (full static budget).
// ws layout: ws_ph [2048][512] then ws_score [2048][64].
__global__ __launch_bounds__(256) void attn_fused(
    const float* __restrict__ features, const float* __restrict__ hidden,
    const float* __restrict__ W1, const float* __restrict__ b1,
    const float* __restrict__ W2, const float* __restrict__ b2,
    const float* __restrict__ Vw, const float* __restrict__ bv,
    float* __restrict__ ctx_out, float* __restrict__ w_out,
    float* __restrict__ ws_ph, float* __restrict__ ws_score)
{
    const int b   = blockIdx.x;
    const int tid = threadIdx.x;
    const int tx  = tid & 31;
    const int ty  = tid >> 5;

    __shared__ float A[LDIM * EDIM];  // 64 KB

    // ---- Stage features[b] (64x256) into LDS, float4 coalesced ----
    {
        const float4* src = (const float4*)(features + (size_t)b * LDIM * EDIM);
        float4* dst = (float4*)A;
#pragma unroll
        for (int i = 0; i < 16; ++i) {
            dst[i * 256 + tid] = src[i * 256 + tid];
        }
    }

    // ---- Fused proj_h: ph[u] = hidden[b]@W2[:,u] + b1[u] + b2[u] ----
    // Thread handles u = 2*tid, 2*tid+1. W2 float2 loads are coalesced.
    {
        const float* h = hidden + (size_t)b * UDIM;
        const int u2 = tid * 2;
        float acc0 = 0.f, acc1 = 0.f;
#pragma unroll 4
        for (int k = 0; k < UDIM; ++k) {
            const float hv = h[k];  // uniform -> scalar load
            const float2 w2 = *(const float2*)(W2 + (size_t)k * UDIM + u2);
            acc0 = fmaf(hv, w2.x, acc0);
            acc1 = fmaf(hv, w2.y, acc1);
        }
        const float2 bb1 = *(const float2*)(b1 + u2);
        const float2 bb2 = *(const float2*)(b2 + u2);
        float2 out;
        out.x = acc0 + bb1.x + bb2.x;
        out.y = acc1 + bb1.y + bb2.y;
        *(float2*)(ws_ph + (size_t)b * UDIM + u2) = out;
    }
    __syncthreads();  // A staged + ws_ph visible to block

    // ---- Main: proj_f = A @ W1, fused tanh + V-dot ----
    // 4 column chunks of 128. Thread tile: 8 rows x 4 cols.
    float sp[8];
#pragma unroll
    for (int j = 0; j < 8; ++j) sp[j] = 0.f;

    const float4* W1v = (const float4*)W1;  // [256][128] of float4

    for (int chunk = 0; chunk < 4; ++chunk) {
        const int u0 = chunk * 128 + tx * 4;
        const int uq = u0 >> 2;  // float4 column index
        float acc[8][4];
#pragma unroll
        for (int j = 0; j < 8; ++j)
#pragma unroll
            for (int i = 0; i < 4; ++i) acc[j][i] = 0.f;

        for (int k = 0; k < EDIM; k += 4) {
            const float4 w0 = W1v[(size_t)(k + 0) * 128 + uq];
            const float4 w1 = W1v[(size_t)(k + 1) * 128 + uq];
            const float4 w2 = W1v[(size_t)(k + 2) * 128 + uq];
            const float4 w3 = W1v[(size_t)(k + 3) * 128 + uq];
#pragma unroll
            for (int j = 0; j < 8; ++j) {
                const float4 a = *(const float4*)(A + (ty * 8 + j) * EDIM + k);
                acc[j][0] = fmaf(a.x, w0.x, acc[j][0]);
                acc[j][0] = fmaf(a.y, w1.x, acc[j][0]);
                acc[j][0] = fmaf(a.z, w2.x, acc[j][0]);
                acc[j][0] = fmaf(a.w, w3.x, acc[j][0]);
                acc[j][1] = fmaf(a.x, w0.y, acc[j][1]);
                acc[j][1] = fmaf(a.y, w1.y, acc[j][1]);
                acc[j][1] = fmaf(a.z, w2.y, acc[j][1]);
                acc[j][1] = fmaf(a.w, w3.y, acc[j][1]);
                acc[j][2] = fmaf(a.x, w0.z, acc[j][2]);
                acc[j][2] = fmaf(a.y, w1.z, acc[j][2]);
                acc[j][2] = fmaf(a.z, w2.z, acc[j][2]);
                acc[j][2] = fmaf(a.w, w3.z, acc[j][2]);
                acc[j][3] = fmaf(a.x, w0.w, acc[j][3]);
                acc[j][3] = fmaf(a.y, w1.w, acc[j][3]);
                acc[j][3] = fmaf(a.z, w2.w, acc[j][3]);
                acc[j][3] = fmaf(a.w, w3.w, acc[j][3]);
            }
        }

        // Chunk epilogue: add ph, tanh, dot with V, accumulate per-row score.
        const float4 ph4 = *(const float4*)(ws_ph + (size_t)b * UDIM + u0);
        const float4 V4  = *(const float4*)(Vw + u0);
#pragma unroll
        for (int j = 0; j < 8; ++j) {
            const float t0 = tanhf(acc[j][0] + ph4.x);
            const float t1 = tanhf(acc[j][1] + ph4.y);
            const float t2 = tanhf(acc[j][2] + ph4.z);
            const float t3 = tanhf(acc[j][3] + ph4.w);
            sp[j] += t0 * V4.x + t1 * V4.y + t2 * V4.z + t3 * V4.w;
        }
    }

    // ---- Reduce scores across tx (butterfly within half-wave, 32 lanes) ----
#pragma unroll
    for (int j = 0; j < 8; ++j) {
        float v = sp[j];
        v += __shfl_xor(v, 1);
        v += __shfl_xor(v, 2);
        v += __shfl_xor(v, 4);
        v += __shfl_xor(v, 8);
        v += __shfl_xor(v, 16);
        if (tx == 0) ws_score[(size_t)b * LDIM + ty * 8 + j] = v;
    }
    __syncthreads();

    // ---- Softmax over L=64 by wave 0 ----
    if (tid < 64) {
        const float s = ws_score[(size_t)b * LDIM + tid] + bv[0];
        float m = s;
        m = fmaxf(m, __shfl_xor(m, 32));
        m = fmaxf(m, __shfl_xor(m, 16));
        m = fmaxf(m, __shfl_xor(m, 8));
        m = fmaxf(m, __shfl_xor(m, 4));
        m = fmaxf(m, __shfl_xor(m, 2));
        m = fmaxf(m, __shfl_xor(m, 1));
        const float e = expf(s - m);
        float sum = e;
        sum += __shfl_xor(sum, 32);
        sum += __shfl_xor(sum, 16);
        sum += __shfl_xor(sum, 8);
        sum += __shfl_xor(sum, 4);
        sum += __shfl_xor(sum, 2);
        sum += __shfl_xor(sum, 1);
        w_out[(size_t)b * LDIM + tid] = e / sum;
    }
    __syncthreads();

    // ---- Context: ctx[b][e] = sum_l w[l] * A[l][e], e = tid ----
    {
        const float* wv = w_out + (size_t)b * LDIM;
        float c = 0.f;
#pragma unroll 8
        for (int l = 0; l < LDIM; ++l) {
            c = fmaf(wv[l], A[l * EDIM + tid], c);
        }
        ctx_out[(size_t)b * EDIM + tid] = c;
    }
}

extern "C" void kernel_launch(void* const* d_in, const int* in_sizes, int n_in,
                              void* d_out, int out_size, void* d_ws, size_t ws_size,
                              hipStream_t stream) {
    const float* features = (const float*)d_in[0];  // [2048, 64, 256]
    const float* hidden   = (const float*)d_in[1];  // [2048, 512]
    const float* W1       = (const float*)d_in[2];  // [256, 512]
    const float* b1       = (const float*)d_in[3];  // [512]
    const float* W2       = (const float*)d_in[4];  // [512, 512]
    const float* b2       = (const float*)d_in[5];  // [512]
    const float* Vw       = (const float*)d_in[6];  // [512, 1]
    const float* bv       = (const float*)d_in[7];  // [1]

    float* ctx_out = (float*)d_out;                       // [2048, 256]
    float* w_out   = (float*)d_out + (size_t)BATCH * EDIM; // [2048, 64, 1]

    float* ws_ph    = (float*)d_ws;                        // [2048][512]
    float* ws_score = ws_ph + (size_t)BATCH * UDIM;        // [2048][64]

    attn_fused<<<dim3(BATCH), dim3(256), 0, stream>>>(
        features, hidden, W1, b1, W2, b2, Vw, bv,
        ctx_out, w_out, ws_ph, ws_score);
}

// Round 2
// 361.508 us; speedup vs baseline: 2.4844x; 2.4844x over previous
//
#include <hip/hip_runtime.h>
#include <math.h>

#define BATCH 2048
#define LDIM 64
#define EDIM 256
#define UDIM 512

typedef __attribute__((ext_vector_type(8))) short short8;
typedef __attribute__((ext_vector_type(4))) float floatx4;

__device__ inline unsigned short f2bf(float f) {
    unsigned u = __builtin_bit_cast(unsigned, f);
    u = (u + 0x7FFFu + ((u >> 16) & 1u)) >> 16;
    return (unsigned short)u;
}
__device__ inline float bf2f(unsigned short h) {
    unsigned u = ((unsigned)h) << 16;
    return __builtin_bit_cast(float, u);
}
__device__ inline float tanh_fast(float x) {
    // tanh(x) = 1 - 2/(exp(2x)+1); exp(2x) = 2^(x*2*log2 e)
    float t = __builtin_amdgcn_exp2f(x * 2.88539008177792681f);
    return 1.f - 2.f * __builtin_amdgcn_rcpf(t + 1.f);
}
__device__ inline void gload16(const void* g, void* l) {
    // async global->LDS, 16 B per lane; LDS dest = uniform base + lane*16
    __builtin_amdgcn_global_load_lds((const __attribute__((address_space(1))) void*)g,
                                     (__attribute__((address_space(3))) void*)l,
                                     16, 0, 0);
}

// ---- prep 1: W1 [256][512] fp32 -> bf16 hi/lo in MFMA-B fragment-linear order ----
// Layout: W[kc(8)][nt(32)][lane(64)][j(8)], value = W1[kc*32 + (lane>>4)*8 + j][nt*16 + (lane&15)]
__global__ __launch_bounds__(256) void prep_w1(const float* __restrict__ W1,
                                               unsigned short* __restrict__ Whi,
                                               unsigned short* __restrict__ Wlo) {
    int t = blockIdx.x * 256 + threadIdx.x;  // 16384 threads
    int lane = t & 63;
    int nt = (t >> 6) & 31;
    int kc = t >> 11;
    int n  = nt * 16 + (lane & 15);
    int k0 = kc * 32 + ((lane >> 4) << 3);
    size_t base = (size_t)t << 3;
#pragma unroll
    for (int j = 0; j < 8; ++j) {
        float w = W1[(size_t)(k0 + j) * UDIM + n];
        unsigned short hi = f2bf(w);
        float lo = w - bf2f(hi);
        Whi[base + j] = hi;
        Wlo[base + j] = f2bf(lo);
    }
}

// ---- prep 2: ph[b][u] = hidden[b]@W2[:,u] + b1[u] + b2[u] ----
// 256 blocks x 8 rows each; thread computes 2 columns for all 8 rows.
__global__ __launch_bounds__(256) void prep_ph(const float* __restrict__ hidden,
                                               const float* __restrict__ W2,
                                               const float* __restrict__ b1,
                                               const float* __restrict__ b2,
                                               float* __restrict__ ph) {
    __shared__ float lh[8 * UDIM];
    const int tid = threadIdx.x;
    const int r0 = blockIdx.x * 8;
    const float4* hs = (const float4*)(hidden + (size_t)r0 * UDIM);
    float4* ld = (float4*)lh;
#pragma unroll
    for (int i = 0; i < 4; ++i) ld[tid + i * 256] = hs[tid + i * 256];
    __syncthreads();
    const int u = tid * 2;
    float acc[8][2] = {};
    for (int k = 0; k < UDIM; ++k) {
        float2 w2 = *(const float2*)(W2 + (size_t)k * UDIM + u);
#pragma unroll
        for (int r = 0; r < 8; ++r) {
            float hv = lh[r * UDIM + k];
            acc[r][0] = fmaf(hv, w2.x, acc[r][0]);
            acc[r][1] = fmaf(hv, w2.y, acc[r][1]);
        }
    }
    const float ba = b1[u] + b2[u];
    const float bb = b1[u + 1] + b2[u + 1];
#pragma unroll
    for (int r = 0; r < 8; ++r) {
        float2 o;
        o.x = acc[r][0] + ba;
        o.y = acc[r][1] + bb;
        *(float2*)(ph + (size_t)(r0 + r) * UDIM + u) = o;
    }
}

// ---- main: per block = one batch b. MFMA split-bf16 GEMM + tanh/V + softmax + context ----
__global__ __launch_bounds__(256, 2) void attn_main(
    const float* __restrict__ feat, const unsigned short* __restrict__ Whi,
    const unsigned short* __restrict__ Wlo, const float* __restrict__ ph,
    const float* __restrict__ Vw, const float* __restrict__ bv,
    float* __restrict__ ctx_out, float* __restrict__ w_out)
{
    extern __shared__ char smem[];
    unsigned short* lBhi = (unsigned short*)smem;   // [32 nt][64][8] = 32 KB
    unsigned short* lBlo = lBhi + 32 * 64 * 8;      // 32 KB
    unsigned short* lAhi = lBlo + 32 * 64 * 8;      // [4 mt][64][8] = 4 KB
    unsigned short* lAlo = lAhi + 4 * 64 * 8;       // 4 KB
    float* phl = (float*)(lAlo + 4 * 64 * 8);       // 512 f
    float* Vl  = phl + 512;                         // 512 f
    float* scp = Vl + 512;                          // 256 f (4 waves x 64 rows)
    float* wsm = scp + 256;                         // 64 f
    // total = 65536 + 8192 + 2048 + 2048 + 1024 + 256 = 79104 B

    const int tid = threadIdx.x;
    const int w   = tid >> 6;
    const int l   = tid & 63;
    const int b   = blockIdx.x;
    const float* fb = feat + (size_t)b * (LDIM * EDIM);

    // stage ph + V (512 floats each)
    {
        const float2* p2 = (const float2*)(ph + (size_t)b * UDIM);
        ((float2*)phl)[tid] = p2[tid];
        ((float2*)Vl)[tid]  = ((const float2*)Vw)[tid];
    }

    floatx4 acc[8][4];  // [nt_local][mt]
#pragma unroll
    for (int i = 0; i < 8; ++i)
#pragma unroll
        for (int j = 0; j < 4; ++j) acc[i][j] = (floatx4){0.f, 0.f, 0.f, 0.f};

    // A-staging geometry: thread -> (row, k-octet)
    const int am    = tid >> 2;
    const int aoct  = tid & 3;
    const int alane = (am & 15) | (aoct << 4);
    const int amt   = am >> 4;
    unsigned short* aWhi = lAhi + (((amt * 64) + alane) << 3);
    unsigned short* aWlo = lAlo + (((amt * 64) + alane) << 3);
    const float* aSrc = fb + am * EDIM + aoct * 8;

    for (int kc = 0; kc < 8; ++kc) {
        __syncthreads();  // previous compute done reading LDS
        // ---- stage B: wave w stages its own nt in [8w, 8w+8) via async global->LDS ----
        {
            const int ntbase = w * 8;
            const unsigned short* gh = Whi + ((((size_t)kc * 32 + ntbase) * 64 + l) << 3);
            const unsigned short* gl = Wlo + ((((size_t)kc * 32 + ntbase) * 64 + l) << 3);
            unsigned short* dh = lBhi + ((ntbase * 64) << 3);
            unsigned short* dl = lBlo + ((ntbase * 64) << 3);
#pragma unroll
            for (int i = 0; i < 8; ++i) {
                gload16(gh + i * 512, dh + i * 512);
                gload16(gl + i * 512, dl + i * 512);
            }
        }
        // ---- stage A: fp32 -> bf16 hi/lo, fragment order ----
        {
            const float4 f0 = *(const float4*)(aSrc + kc * 32);
            const float4 f1 = *(const float4*)(aSrc + kc * 32 + 4);
            float fv[8] = {f0.x, f0.y, f0.z, f0.w, f1.x, f1.y, f1.z, f1.w};
            short8 hi, lo;
#pragma unroll
            for (int j = 0; j < 8; ++j) {
                unsigned short h = f2bf(fv[j]);
                hi[j] = (short)h;
                lo[j] = (short)f2bf(fv[j] - bf2f(h));
            }
            *(short8*)aWhi = hi;
            *(short8*)aWlo = lo;
        }
        __syncthreads();  // staging (incl. global_load_lds) drained

        // ---- compute: 4 m-tiles x 8 n-tiles x 3 MFMAs ----
        short8 ah[4], al[4];
#pragma unroll
        for (int mt = 0; mt < 4; ++mt) {
            ah[mt] = *(const short8*)(lAhi + ((mt * 64 + l) << 3));
            al[mt] = *(const short8*)(lAlo + ((mt * 64 + l) << 3));
        }
#pragma unroll
        for (int nt = 0; nt < 8; ++nt) {
            const int ntg = w * 8 + nt;
            short8 bh = *(const short8*)(lBhi + ((ntg * 64 + l) << 3));
            short8 bl = *(const short8*)(lBlo + ((ntg * 64 + l) << 3));
#pragma unroll
            for (int mt = 0; mt < 4; ++mt) {
                acc[nt][mt] = __builtin_amdgcn_mfma_f32_16x16x32_bf16(ah[mt], bh, acc[nt][mt], 0, 0, 0);
                acc[nt][mt] = __builtin_amdgcn_mfma_f32_16x16x32_bf16(al[mt], bh, acc[nt][mt], 0, 0, 0);
                acc[nt][mt] = __builtin_amdgcn_mfma_f32_16x16x32_bf16(ah[mt], bl, acc[nt][mt], 0, 0, 0);
            }
        }
    }

    // ---- epilogue: tanh(acc + ph) * V, accumulate per-row score partials ----
    float sv[4][4];
#pragma unroll
    for (int mt = 0; mt < 4; ++mt)
#pragma unroll
        for (int r = 0; r < 4; ++r) sv[mt][r] = 0.f;

#pragma unroll
    for (int nt = 0; nt < 8; ++nt) {
        const int n = w * 128 + nt * 16 + (l & 15);
        const float phn = phl[n];
        const float vn  = Vl[n];
#pragma unroll
        for (int mt = 0; mt < 4; ++mt)
#pragma unroll
            for (int r = 0; r < 4; ++r)
                sv[mt][r] += tanh_fast(acc[nt][mt][r] + phn) * vn;
    }
    // reduce over the 16 columns held by lanes (l&15)
#pragma unroll
    for (int mt = 0; mt < 4; ++mt)
#pragma unroll
        for (int r = 0; r < 4; ++r) {
            float v = sv[mt][r];
            v += __shfl_xor(v, 1);
            v += __shfl_xor(v, 2);
            v += __shfl_xor(v, 4);
            v += __shfl_xor(v, 8);
            sv[mt][r] = v;
        }
    if ((l & 15) == 0) {
        const int q = l >> 4;
#pragma unroll
        for (int mt = 0; mt < 4; ++mt)
#pragma unroll
            for (int r = 0; r < 4; ++r)
                scp[w * 64 + mt * 16 + q * 4 + r] = sv[mt][r];
    }
    __syncthreads();

    // ---- softmax over L=64 (wave 0) ----
    if (tid < 64) {
        float s = scp[tid] + scp[64 + tid] + scp[128 + tid] + scp[192 + tid] + bv[0];
        float m = s;
        m = fmaxf(m, __shfl_xor(m, 32));
        m = fmaxf(m, __shfl_xor(m, 16));
        m = fmaxf(m, __shfl_xor(m, 8));
        m = fmaxf(m, __shfl_xor(m, 4));
        m = fmaxf(m, __shfl_xor(m, 2));
        m = fmaxf(m, __shfl_xor(m, 1));
        float e = __builtin_amdgcn_exp2f((s - m) * 1.44269504088896341f);
        float sum = e;
        sum += __shfl_xor(sum, 32);
        sum += __shfl_xor(sum, 16);
        sum += __shfl_xor(sum, 8);
        sum += __shfl_xor(sum, 4);
        sum += __shfl_xor(sum, 2);
        sum += __shfl_xor(sum, 1);
        float wgt = e / sum;
        wsm[tid] = wgt;
        w_out[(size_t)b * LDIM + tid] = wgt;
    }
    __syncthreads();

    // ---- context: ctx[b][e] = sum_l wsm[l] * feat[b][l][e], e = tid ----
    {
        float c = 0.f;
#pragma unroll 8
        for (int ll = 0; ll < LDIM; ++ll)
            c = fmaf(wsm[ll], fb[ll * EDIM + tid], c);
        ctx_out[(size_t)b * EDIM + tid] = c;
    }
}

extern "C" void kernel_launch(void* const* d_in, const int* in_sizes, int n_in,
                              void* d_out, int out_size, void* d_ws, size_t ws_size,
                              hipStream_t stream) {
    const float* features = (const float*)d_in[0];
    const float* hidden   = (const float*)d_in[1];
    const float* W1       = (const float*)d_in[2];
    const float* b1       = (const float*)d_in[3];
    const float* W2       = (const float*)d_in[4];
    const float* b2       = (const float*)d_in[5];
    const float* Vw       = (const float*)d_in[6];
    const float* bv       = (const float*)d_in[7];

    float* ctx_out = (float*)d_out;                         // [2048,256]
    float* w_out   = (float*)d_out + (size_t)BATCH * EDIM;  // [2048,64,1]

    float* ph = (float*)d_ws;                               // 4 MB
    unsigned short* Whi = (unsigned short*)(ph + (size_t)BATCH * UDIM);  // 256 KB
    unsigned short* Wlo = Whi + 8 * 32 * 64 * 8;            // 256 KB

    prep_w1<<<dim3(64), dim3(256), 0, stream>>>(W1, Whi, Wlo);
    prep_ph<<<dim3(256), dim3(256), 0, stream>>>(hidden, W2, b1, b2, ph);

    const int smem = 79104;
    hipFuncSetAttribute((const void*)attn_main,
                        hipFuncAttributeMaxDynamicSharedMemorySize, 81920);
    attn_main<<<dim3(BATCH), dim3(256), smem, stream>>>(
        features, Whi, Wlo, ph, Vw, bv, ctx_out, w_out);
}

// Round 3
// 337.734 us; speedup vs baseline: 2.6592x; 1.0704x over previous
//
#include <hip/hip_runtime.h>
#include <math.h>

#define BATCH 2048
#define LDIM 64
#define EDIM 256
#define UDIM 512

typedef __attribute__((ext_vector_type(8))) short short8;
typedef __attribute__((ext_vector_type(4))) float floatx4;

__device__ inline unsigned short f2bf(float f) {
    unsigned u = __builtin_bit_cast(unsigned, f);
    u = (u + 0x7FFFu + ((u >> 16) & 1u)) >> 16;
    return (unsigned short)u;
}
__device__ inline float bf2f(unsigned short h) {
    unsigned u = ((unsigned)h) << 16;
    return __builtin_bit_cast(float, u);
}
__device__ inline float tanh_fast(float x) {
    float t = __builtin_amdgcn_exp2f(x * 2.88539008177792681f);
    return 1.f - 2.f * __builtin_amdgcn_rcpf(t + 1.f);
}
// Split fp32 -> (hi, lo) bf16 pair for one 8-element k-octet.
__device__ inline void split8(const float4 f0, const float4 f1, short8& hi, short8& lo) {
    float fv[8] = {f0.x, f0.y, f0.z, f0.w, f1.x, f1.y, f1.z, f1.w};
#pragma unroll
    for (int j = 0; j < 8; ++j) {
        unsigned short h = f2bf(fv[j]);
        hi[j] = (short)h;
        lo[j] = (short)f2bf(fv[j] - bf2f(h));
    }
}
// B-fragment pointer: layout [kc][ntg(32)][lane(64)][8]
__device__ inline const short8* bfrag(const unsigned short* W, int kc, int ntg, int l) {
    return (const short8*)(W + ((((size_t)kc * 32 + ntg) * 64 + l) << 3));
}

// ---- prep: W[K][512] fp32 -> bf16 hi/lo fragment-linear. grid = K*64/256 blocks ----
__global__ __launch_bounds__(256) void prep_w(const float* __restrict__ W,
                                              unsigned short* __restrict__ Whi,
                                              unsigned short* __restrict__ Wlo) {
    int t = blockIdx.x * 256 + threadIdx.x;
    int lane = t & 63;
    int nt = (t >> 6) & 31;
    int kc = t >> 11;
    int n  = nt * 16 + (lane & 15);
    int k0 = kc * 32 + ((lane >> 4) << 3);
    size_t base = (size_t)t << 3;
#pragma unroll
    for (int j = 0; j < 8; ++j) {
        float w = W[(size_t)(k0 + j) * UDIM + n];
        unsigned short hi = f2bf(w);
        Whi[base + j] = hi;
        Wlo[base + j] = f2bf(w - bf2f(hi));
    }
}

// ---- prep_ph via MFMA: ph = hidden @ W2 + b1 + b2.  M=16/block, 128 blocks, no LDS ----
__global__ __launch_bounds__(512) void prep_ph(const float* __restrict__ hidden,
                                               const unsigned short* __restrict__ W2hi,
                                               const unsigned short* __restrict__ W2lo,
                                               const float* __restrict__ b1,
                                               const float* __restrict__ b2,
                                               float* __restrict__ ph) {
    const int tid = threadIdx.x;
    const int w = tid >> 6;       // 8 waves, wave owns cols [64w, 64w+64)
    const int l = tid & 63;
    const int r0 = blockIdx.x * 16;

    floatx4 acc[4];
#pragma unroll
    for (int i = 0; i < 4; ++i) acc[i] = (floatx4){0.f, 0.f, 0.f, 0.f};

    const float* ap = hidden + (size_t)(r0 + (l & 15)) * UDIM + ((l >> 4) << 3);

#pragma unroll 4
    for (int kc = 0; kc < 16; ++kc) {
        const float4 f0 = *(const float4*)(ap + kc * 32);
        const float4 f1 = *(const float4*)(ap + kc * 32 + 4);
        short8 ah, al;
        split8(f0, f1, ah, al);
#pragma unroll
        for (int nt = 0; nt < 4; ++nt) {
            const int ntg = w * 4 + nt;
            short8 bh = *bfrag(W2hi, kc, ntg, l);
            short8 bl = *bfrag(W2lo, kc, ntg, l);
            acc[nt] = __builtin_amdgcn_mfma_f32_16x16x32_bf16(ah, bh, acc[nt], 0, 0, 0);
            acc[nt] = __builtin_amdgcn_mfma_f32_16x16x32_bf16(al, bh, acc[nt], 0, 0, 0);
            acc[nt] = __builtin_amdgcn_mfma_f32_16x16x32_bf16(ah, bl, acc[nt], 0, 0, 0);
        }
    }
#pragma unroll
    for (int nt = 0; nt < 4; ++nt) {
        const int n = w * 64 + nt * 16 + (l & 15);
        const float bias = b1[n] + b2[n];
#pragma unroll
        for (int r = 0; r < 4; ++r) {
            const int m = (l >> 4) * 4 + r;
            ph[(size_t)(r0 + m) * UDIM + n] = acc[nt][r] + bias;
        }
    }
}

// ---- main: block = 2 batches (M=128), 512 threads / 8 waves.
// B fragments in registers (wave-private), A double-buffered in LDS, 1 barrier/kc.
__global__ __launch_bounds__(512, 2) void attn_main(
    const float* __restrict__ feat, const unsigned short* __restrict__ W1hi,
    const unsigned short* __restrict__ W1lo, const float* __restrict__ ph,
    const float* __restrict__ Vw, const float* __restrict__ bv,
    float* __restrict__ ctx_out, float* __restrict__ w_out)
{
    __shared__ unsigned short lAhi[2][4096];  // [buf][mt(8)][lane(64)][8]
    __shared__ unsigned short lAlo[2][4096];
    __shared__ float phl[1024];               // 2 batches x 512
    __shared__ float Vl[512];
    __shared__ float scp[8][128];             // [wave][row128]
    __shared__ float wsm[128];

    const int tid = threadIdx.x;
    const int w = tid >> 6;   // wave owns cols [64w, 64w+64)
    const int l = tid & 63;
    const size_t b0 = (size_t)blockIdx.x * 2;
    const float* fb = feat + b0 * (LDIM * EDIM);  // 128 contiguous rows

    // stage ph (1024 f) + V (512 f)
    ((float2*)phl)[tid] = ((const float2*)(ph + b0 * UDIM))[tid];
    Vl[tid] = Vw[tid];

    // A staging geometry: thread -> (row 0..127, k-octet 0..3)
    const int arow = tid >> 2, aoct = tid & 3;
    const float* aSrc = fb + arow * EDIM + aoct * 8;
    const int aidx = (((arow >> 4) * 64) + (aoct << 4) + (arow & 15)) << 3;

    floatx4 acc[4][8];  // [nt][mt]
#pragma unroll
    for (int i = 0; i < 4; ++i)
#pragma unroll
        for (int j = 0; j < 8; ++j) acc[i][j] = (floatx4){0.f, 0.f, 0.f, 0.f};

    short8 Bh[2][4];  // double-buffered hi B frags
    short8 Bl[4];     // just-in-time lo B frags
    float4 fA[2][2];  // prefetched fp32 A octets

    // ---- prologue: kc=0 ----
    fA[0][0] = *(const float4*)(aSrc);
    fA[0][1] = *(const float4*)(aSrc + 4);
#pragma unroll
    for (int nt = 0; nt < 4; ++nt) Bh[0][nt] = *bfrag(W1hi, 0, w * 4 + nt, l);
    {
        short8 hi, lo;
        split8(fA[0][0], fA[0][1], hi, lo);
        *(short8*)&lAhi[0][aidx] = hi;
        *(short8*)&lAlo[0][aidx] = lo;
    }
    __syncthreads();

#pragma unroll
    for (int kc = 0; kc < 8; ++kc) {
        const int cur = kc & 1, nxt = cur ^ 1;
        // JIT lo-B for this kc (arrives during pass 1)
#pragma unroll
        for (int nt = 0; nt < 4; ++nt) Bl[nt] = *bfrag(W1lo, kc, w * 4 + nt, l);
        // prefetch next kc (drained by the barrier at loop bottom)
        if (kc < 7) {
            fA[nxt][0] = *(const float4*)(aSrc + (kc + 1) * 32);
            fA[nxt][1] = *(const float4*)(aSrc + (kc + 1) * 32 + 4);
#pragma unroll
            for (int nt = 0; nt < 4; ++nt) Bh[nxt][nt] = *bfrag(W1hi, kc + 1, w * 4 + nt, l);
        }
        // compute, 2 blocks of 4 m-tiles
#pragma unroll
        for (int mh = 0; mh < 2; ++mh) {
            short8 ah[4], al[4];
#pragma unroll
            for (int i = 0; i < 4; ++i) {
                ah[i] = *(const short8*)&lAhi[cur][((mh * 4 + i) * 64 + l) << 3];
                al[i] = *(const short8*)&lAlo[cur][((mh * 4 + i) * 64 + l) << 3];
            }
#pragma unroll
            for (int nt = 0; nt < 4; ++nt)
#pragma unroll
                for (int i = 0; i < 4; ++i)
                    acc[nt][mh * 4 + i] = __builtin_amdgcn_mfma_f32_16x16x32_bf16(
                        ah[i], Bh[cur][nt], acc[nt][mh * 4 + i], 0, 0, 0);
#pragma unroll
            for (int nt = 0; nt < 4; ++nt)
#pragma unroll
                for (int i = 0; i < 4; ++i)
                    acc[nt][mh * 4 + i] = __builtin_amdgcn_mfma_f32_16x16x32_bf16(
                        ah[i], Bl[nt], acc[nt][mh * 4 + i], 0, 0, 0);
#pragma unroll
            for (int nt = 0; nt < 4; ++nt)
#pragma unroll
                for (int i = 0; i < 4; ++i)
                    acc[nt][mh * 4 + i] = __builtin_amdgcn_mfma_f32_16x16x32_bf16(
                        al[i], Bh[cur][nt], acc[nt][mh * 4 + i], 0, 0, 0);
        }
        // stage A(kc+1) into other buffer
        if (kc < 7) {
            short8 hi, lo;
            split8(fA[nxt][0], fA[nxt][1], hi, lo);
            *(short8*)&lAhi[nxt][aidx] = hi;
            *(short8*)&lAlo[nxt][aidx] = lo;
        }
        __syncthreads();
    }

    // ---- epilogue: score partials ----
    float sv[8][4];
#pragma unroll
    for (int mt = 0; mt < 8; ++mt)
#pragma unroll
        for (int r = 0; r < 4; ++r) sv[mt][r] = 0.f;

#pragma unroll
    for (int nt = 0; nt < 4; ++nt) {
        const int n = w * 64 + nt * 16 + (l & 15);
        const float vn  = Vl[n];
        const float ph0 = phl[n];
        const float ph1 = phl[512 + n];
#pragma unroll
        for (int mt = 0; mt < 8; ++mt) {
            const float phv = (mt < 4) ? ph0 : ph1;
#pragma unroll
            for (int r = 0; r < 4; ++r)
                sv[mt][r] += tanh_fast(acc[nt][mt][r] + phv) * vn;
        }
    }
#pragma unroll
    for (int mt = 0; mt < 8; ++mt)
#pragma unroll
        for (int r = 0; r < 4; ++r) {
            float v = sv[mt][r];
            v += __shfl_xor(v, 1);
            v += __shfl_xor(v, 2);
            v += __shfl_xor(v, 4);
            v += __shfl_xor(v, 8);
            if ((l & 15) == 0) scp[w][mt * 16 + (l >> 4) * 4 + r] = v;
        }
    __syncthreads();

    // ---- softmax: wave 0 -> batch 0, wave 1 -> batch 1 ----
    if (tid < 128) {
        float s = bv[0];
#pragma unroll
        for (int wv = 0; wv < 8; ++wv) s += scp[wv][tid];
        float m = s;
        m = fmaxf(m, __shfl_xor(m, 32));
        m = fmaxf(m, __shfl_xor(m, 16));
        m = fmaxf(m, __shfl_xor(m, 8));
        m = fmaxf(m, __shfl_xor(m, 4));
        m = fmaxf(m, __shfl_xor(m, 2));
        m = fmaxf(m, __shfl_xor(m, 1));
        float e = __builtin_amdgcn_exp2f((s - m) * 1.44269504088896341f);
        float sum = e;
        sum += __shfl_xor(sum, 32);
        sum += __shfl_xor(sum, 16);
        sum += __shfl_xor(sum, 8);
        sum += __shfl_xor(sum, 4);
        sum += __shfl_xor(sum, 2);
        sum += __shfl_xor(sum, 1);
        float wgt = e / sum;
        wsm[tid] = wgt;
        w_out[b0 * LDIM + tid] = wgt;
    }
    __syncthreads();

    // ---- context: threads 0..255 batch0, 256..511 batch1 ----
    {
        const int bb = tid >> 8, e = tid & 255;
        const float* fbb = fb + bb * (LDIM * EDIM);
        const float* wv = wsm + bb * 64;
        float c = 0.f;
#pragma unroll 8
        for (int ll = 0; ll < LDIM; ++ll)
            c = fmaf(wv[ll], fbb[ll * EDIM + e], c);
        ctx_out[(b0 + bb) * EDIM + e] = c;
    }
}

extern "C" void kernel_launch(void* const* d_in, const int* in_sizes, int n_in,
                              void* d_out, int out_size, void* d_ws, size_t ws_size,
                              hipStream_t stream) {
    const float* features = (const float*)d_in[0];
    const float* hidden   = (const float*)d_in[1];
    const float* W1       = (const float*)d_in[2];
    const float* b1       = (const float*)d_in[3];
    const float* W2       = (const float*)d_in[4];
    const float* b2       = (const float*)d_in[5];
    const float* Vw       = (const float*)d_in[6];
    const float* bv       = (const float*)d_in[7];

    float* ctx_out = (float*)d_out;                         // [2048,256]
    float* w_out   = (float*)d_out + (size_t)BATCH * EDIM;  // [2048,64,1]

    float* ph = (float*)d_ws;                                          // 4 MB
    unsigned short* W1hi = (unsigned short*)(ph + (size_t)BATCH * UDIM);
    unsigned short* W1lo = W1hi + (size_t)8  * 32 * 64 * 8;   // 256 KB each
    unsigned short* W2hi = W1lo + (size_t)8  * 32 * 64 * 8;
    unsigned short* W2lo = W2hi + (size_t)16 * 32 * 64 * 8;   // 512 KB each

    prep_w<<<dim3(64),  dim3(256), 0, stream>>>(W1, W1hi, W1lo);
    prep_w<<<dim3(128), dim3(256), 0, stream>>>(W2, W2hi, W2lo);
    prep_ph<<<dim3(128), dim3(512), 0, stream>>>(hidden, W2hi, W2lo, b1, b2, ph);
    attn_main<<<dim3(BATCH / 2), dim3(512), 0, stream>>>(
        features, W1hi, W1lo, ph, Vw, bv, ctx_out, w_out);
}

// Round 4
// 261.327 us; speedup vs baseline: 3.4367x; 1.2924x over previous
//
#include <hip/hip_runtime.h>
#include <math.h>

#define BATCH 2048
#define LDIM 64
#define EDIM 256
#define UDIM 512

typedef __attribute__((ext_vector_type(8))) _Float16 half8;
typedef __attribute__((ext_vector_type(4))) float floatx4;

__device__ inline float tanh_fast(float x) {
    float t = __builtin_amdgcn_exp2f(x * 2.88539008177792681f);
    return 1.f - 2.f * __builtin_amdgcn_rcpf(t + 1.f);
}
__device__ inline half8 cvt8(float4 f0, float4 f1) {
    half8 h;
    h[0] = (_Float16)f0.x; h[1] = (_Float16)f0.y;
    h[2] = (_Float16)f0.z; h[3] = (_Float16)f0.w;
    h[4] = (_Float16)f1.x; h[5] = (_Float16)f1.y;
    h[6] = (_Float16)f1.z; h[7] = (_Float16)f1.w;
    return h;
}
// B-fragment pointer: layout [kc][ntg(32)][lane(64)][8 fp16]
__device__ inline const half8* bfrag(const unsigned short* F, int kc, int ntg, int l) {
    return (const half8*)(F + ((((size_t)kc * 32 + ntg) * 64 + l) << 3));
}

// ---- prep: W[K][512] fp32 -> fp16 B-fragments via coalesced LDS slab.
// Block = (matrix, kc, col-group of 128). W1: 8 kc x 4 grp = 32 blocks; W2: 16 x 4 = 64.
__global__ __launch_bounds__(256) void prep_frag(const float* __restrict__ W1,
                                                 const float* __restrict__ W2,
                                                 unsigned short* __restrict__ F1,
                                                 unsigned short* __restrict__ F2) {
    __shared__ float S[32 * 128];  // 16 KB slab
    int bid = blockIdx.x;
    const float* W; unsigned short* F; int kc, grp;
    if (bid < 32) { W = W1; F = F1; kc = bid >> 2; grp = bid & 3; }
    else { bid -= 32; W = W2; F = F2; kc = bid >> 2; grp = bid & 3; }
    const int tid = threadIdx.x;
    const float* src = W + (size_t)kc * 32 * UDIM + grp * 128;
    float4* Sv = (float4*)S;
#pragma unroll
    for (int i = 0; i < 4; ++i) {
        int f = tid + i * 256;         // 0..1023
        int k = f >> 5, c4 = f & 31;   // row, float4-col
        Sv[f] = *(const float4*)(src + (size_t)k * UDIM + c4 * 4);
    }
    __syncthreads();
#pragma unroll
    for (int i = 0; i < 2; ++i) {
        int u = tid + i * 256;         // unit = ntl*64 + lane
        int lane = u & 63, ntl = u >> 6;
        int n_loc = ntl * 16 + (lane & 15);
        int k0 = (lane >> 4) * 8;
        half8 h;
#pragma unroll
        for (int j = 0; j < 8; ++j)
            h[j] = (_Float16)S[(k0 + j) * 128 + n_loc];
        int ntg = grp * 8 + ntl;
        *(half8*)(F + (((size_t)kc * 32 + ntg) * 64 + lane) * 8) = h;
    }
}

// ---- prep_ph: ph = hidden @ W2 + b1 + b2 via fp16 MFMA. M=16/block, 128 blocks. ----
__global__ __launch_bounds__(256) void prep_ph(const float* __restrict__ hidden,
                                               const unsigned short* __restrict__ F2,
                                               const float* __restrict__ b1,
                                               const float* __restrict__ b2,
                                               float* __restrict__ ph) {
    const int tid = threadIdx.x;
    const int w = tid >> 6;   // 4 waves, wave covers ntg in [8w, 8w+8)
    const int l = tid & 63;
    const int r0 = blockIdx.x * 16;

    floatx4 acc[8];
#pragma unroll
    for (int i = 0; i < 8; ++i) acc[i] = (floatx4){0.f, 0.f, 0.f, 0.f};

    const float* ap = hidden + (size_t)(r0 + (l & 15)) * UDIM + ((l >> 4) << 3);

    float4 a0 = *(const float4*)(ap);
    float4 a1 = *(const float4*)(ap + 4);
    half8 B[8];
#pragma unroll
    for (int nt = 0; nt < 8; ++nt) B[nt] = *bfrag(F2, 0, w * 8 + nt, l);

    for (int kc = 0; kc < 16; ++kc) {
        half8 a = cvt8(a0, a1);
        float4 n0, n1; half8 NB[8];
        if (kc < 15) {
            n0 = *(const float4*)(ap + (kc + 1) * 32);
            n1 = *(const float4*)(ap + (kc + 1) * 32 + 4);
#pragma unroll
            for (int nt = 0; nt < 8; ++nt) NB[nt] = *bfrag(F2, kc + 1, w * 8 + nt, l);
        }
#pragma unroll
        for (int nt = 0; nt < 8; ++nt)
            acc[nt] = __builtin_amdgcn_mfma_f32_16x16x32_f16(a, B[nt], acc[nt], 0, 0, 0);
        if (kc < 15) {
            a0 = n0; a1 = n1;
#pragma unroll
            for (int nt = 0; nt < 8; ++nt) B[nt] = NB[nt];
        }
    }
#pragma unroll
    for (int nt = 0; nt < 8; ++nt) {
        const int n = (w * 8 + nt) * 16 + (l & 15);
        const float bias = b1[n] + b2[n];
#pragma unroll
        for (int r = 0; r < 4; ++r) {
            const int m = (l >> 4) * 4 + r;
            ph[(size_t)(r0 + m) * UDIM + n] = acc[nt][r] + bias;
        }
    }
}

// ---- main: block = 1 batch (M=64), 256 threads / 4 waves, wave = 128 cols.
// fp16 single MFMA; A double-buffered in LDS; B fragments in registers; 1 barrier/kc.
__global__ __launch_bounds__(256, 2) void attn_main(
    const float* __restrict__ feat, const unsigned short* __restrict__ F1,
    const float* __restrict__ ph, const float* __restrict__ Vw,
    const float* __restrict__ bv,
    float* __restrict__ ctx_out, float* __restrict__ w_out)
{
    __shared__ unsigned short lA[2][4 * 64 * 8];  // 4 KB per buffer
    __shared__ float phl[512];
    __shared__ float Vl[512];
    __shared__ float scp[4][64];
    __shared__ float wsm[64];

    const int tid = threadIdx.x;
    const int w = tid >> 6;
    const int l = tid & 63;
    const size_t b = blockIdx.x;
    const float* fb = feat + b * (LDIM * EDIM);

    ((float2*)phl)[tid] = ((const float2*)(ph + b * UDIM))[tid];
    ((float2*)Vl)[tid]  = ((const float2*)Vw)[tid];

    // A staging: thread -> (row 0..63, k-octet 0..3)
    const int arow = tid >> 2, aoct = tid & 3;
    const float* aSrc = fb + arow * EDIM + aoct * 8;
    const int aidx = (((arow >> 4) * 64) + (aoct << 4) + (arow & 15)) * 8;

    floatx4 acc[8][4];  // [nt][mt]
#pragma unroll
    for (int i = 0; i < 8; ++i)
#pragma unroll
        for (int j = 0; j < 4; ++j) acc[i][j] = (floatx4){0.f, 0.f, 0.f, 0.f};

    // prologue: kc=0
    half8 Bc[8];
#pragma unroll
    for (int nt = 0; nt < 8; ++nt) Bc[nt] = *bfrag(F1, 0, w * 8 + nt, l);
    {
        float4 f0 = *(const float4*)(aSrc);
        float4 f1 = *(const float4*)(aSrc + 4);
        *(half8*)&lA[0][aidx] = cvt8(f0, f1);
    }
    __syncthreads();

#pragma unroll
    for (int kc = 0; kc < 8; ++kc) {
        const int cur = kc & 1;
        float4 n0, n1; half8 Bn[8];
        if (kc < 7) {
            n0 = *(const float4*)(aSrc + (kc + 1) * 32);
            n1 = *(const float4*)(aSrc + (kc + 1) * 32 + 4);
#pragma unroll
            for (int nt = 0; nt < 8; ++nt) Bn[nt] = *bfrag(F1, kc + 1, w * 8 + nt, l);
        }
        half8 a[4];
#pragma unroll
        for (int mt = 0; mt < 4; ++mt)
            a[mt] = *(const half8*)&lA[cur][(mt * 64 + l) * 8];
#pragma unroll
        for (int nt = 0; nt < 8; ++nt)
#pragma unroll
            for (int mt = 0; mt < 4; ++mt)
                acc[nt][mt] = __builtin_amdgcn_mfma_f32_16x16x32_f16(
                    a[mt], Bc[nt], acc[nt][mt], 0, 0, 0);
        if (kc < 7) {
            *(half8*)&lA[cur ^ 1][aidx] = cvt8(n0, n1);
#pragma unroll
            for (int nt = 0; nt < 8; ++nt) Bc[nt] = Bn[nt];
        }
        __syncthreads();
    }

    // epilogue: tanh(acc + ph) * V -> per-row score partials
    float sv[4][4];
#pragma unroll
    for (int mt = 0; mt < 4; ++mt)
#pragma unroll
        for (int r = 0; r < 4; ++r) sv[mt][r] = 0.f;
#pragma unroll
    for (int nt = 0; nt < 8; ++nt) {
        const int n = (w * 8 + nt) * 16 + (l & 15);
        const float phn = phl[n];
        const float vn  = Vl[n];
#pragma unroll
        for (int mt = 0; mt < 4; ++mt)
#pragma unroll
            for (int r = 0; r < 4; ++r)
                sv[mt][r] += tanh_fast(acc[nt][mt][r] + phn) * vn;
    }
#pragma unroll
    for (int mt = 0; mt < 4; ++mt)
#pragma unroll
        for (int r = 0; r < 4; ++r) {
            float v = sv[mt][r];
            v += __shfl_xor(v, 1);
            v += __shfl_xor(v, 2);
            v += __shfl_xor(v, 4);
            v += __shfl_xor(v, 8);
            if ((l & 15) == 0) scp[w][mt * 16 + (l >> 4) * 4 + r] = v;
        }
    __syncthreads();

    // softmax over L=64 (wave 0)
    if (tid < 64) {
        float s = scp[0][tid] + scp[1][tid] + scp[2][tid] + scp[3][tid] + bv[0];
        float m = s;
        m = fmaxf(m, __shfl_xor(m, 32));
        m = fmaxf(m, __shfl_xor(m, 16));
        m = fmaxf(m, __shfl_xor(m, 8));
        m = fmaxf(m, __shfl_xor(m, 4));
        m = fmaxf(m, __shfl_xor(m, 2));
        m = fmaxf(m, __shfl_xor(m, 1));
        float e = __builtin_amdgcn_exp2f((s - m) * 1.44269504088896341f);
        float sum = e;
        sum += __shfl_xor(sum, 32);
        sum += __shfl_xor(sum, 16);
        sum += __shfl_xor(sum, 8);
        sum += __shfl_xor(sum, 4);
        sum += __shfl_xor(sum, 2);
        sum += __shfl_xor(sum, 1);
        float wgt = e / sum;
        wsm[tid] = wgt;
        w_out[b * LDIM + tid] = wgt;
    }
    __syncthreads();

    // context: ctx[b][e] = sum_l wsm[l] * feat[b][l][e], e = tid
    {
        float c = 0.f;
#pragma unroll 8
        for (int ll = 0; ll < LDIM; ++ll)
            c = fmaf(wsm[ll], fb[ll * EDIM + tid], c);
        ctx_out[b * EDIM + tid] = c;
    }
}

extern "C" void kernel_launch(void* const* d_in, const int* in_sizes, int n_in,
                              void* d_out, int out_size, void* d_ws, size_t ws_size,
                              hipStream_t stream) {
    const float* features = (const float*)d_in[0];
    const float* hidden   = (const float*)d_in[1];
    const float* W1       = (const float*)d_in[2];
    const float* b1       = (const float*)d_in[3];
    const float* W2       = (const float*)d_in[4];
    const float* b2       = (const float*)d_in[5];
    const float* Vw       = (const float*)d_in[6];
    const float* bv       = (const float*)d_in[7];

    float* ctx_out = (float*)d_out;                         // [2048,256]
    float* w_out   = (float*)d_out + (size_t)BATCH * EDIM;  // [2048,64,1]

    float* ph = (float*)d_ws;                                   // 4 MB
    unsigned short* F1 = (unsigned short*)(ph + (size_t)BATCH * UDIM);  // 256 KB
    unsigned short* F2 = F1 + (size_t)8 * 32 * 64 * 8;          // 512 KB

    prep_frag<<<dim3(96), dim3(256), 0, stream>>>(W1, W2, F1, F2);
    prep_ph<<<dim3(128), dim3(256), 0, stream>>>(hidden, F2, b1, b2, ph);
    attn_main<<<dim3(BATCH), dim3(256), 0, stream>>>(
        features, F1, ph, Vw, bv, ctx_out, w_out);
}

// Round 5
// 257.498 us; speedup vs baseline: 3.4878x; 1.0149x over previous
//
#include <hip/hip_runtime.h>
#include <math.h>

#define BATCH 2048
#define LDIM 64
#define EDIM 256
#define UDIM 512

typedef __attribute__((ext_vector_type(8))) _Float16 half8;
typedef __attribute__((ext_vector_type(4))) float floatx4;

__device__ inline float tanh_fast(float x) {
    float t = __builtin_amdgcn_exp2f(x * 2.88539008177792681f);
    return 1.f - 2.f * __builtin_amdgcn_rcpf(t + 1.f);
}
__device__ inline half8 cvt8(float4 f0, float4 f1) {
    half8 h;
    h[0] = (_Float16)f0.x; h[1] = (_Float16)f0.y;
    h[2] = (_Float16)f0.z; h[3] = (_Float16)f0.w;
    h[4] = (_Float16)f1.x; h[5] = (_Float16)f1.y;
    h[6] = (_Float16)f1.z; h[7] = (_Float16)f1.w;
    return h;
}
// B-fragment pointer: layout [kc][ntg(32)][lane(64)][8 fp16]
__device__ inline const half8* bfrag(const unsigned short* F, int kc, int ntg, int l) {
    return (const half8*)(F + ((((size_t)kc * 32 + ntg) * 64 + l) << 3));
}

// ---- prep: W[K][512] fp32 -> fp16 B-fragments via coalesced LDS slab. ----
__global__ __launch_bounds__(256) void prep_frag(const float* __restrict__ W1,
                                                 const float* __restrict__ W2,
                                                 unsigned short* __restrict__ F1,
                                                 unsigned short* __restrict__ F2) {
    __shared__ float S[32 * 128];
    int bid = blockIdx.x;
    const float* W; unsigned short* F; int kc, grp;
    if (bid < 32) { W = W1; F = F1; kc = bid >> 2; grp = bid & 3; }
    else { bid -= 32; W = W2; F = F2; kc = bid >> 2; grp = bid & 3; }
    const int tid = threadIdx.x;
    const float* src = W + (size_t)kc * 32 * UDIM + grp * 128;
    float4* Sv = (float4*)S;
#pragma unroll
    for (int i = 0; i < 4; ++i) {
        int f = tid + i * 256;
        int k = f >> 5, c4 = f & 31;
        Sv[f] = *(const float4*)(src + (size_t)k * UDIM + c4 * 4);
    }
    __syncthreads();
#pragma unroll
    for (int i = 0; i < 2; ++i) {
        int u = tid + i * 256;
        int lane = u & 63, ntl = u >> 6;
        int n_loc = ntl * 16 + (lane & 15);
        int k0 = (lane >> 4) * 8;
        half8 h;
#pragma unroll
        for (int j = 0; j < 8; ++j)
            h[j] = (_Float16)S[(k0 + j) * 128 + n_loc];
        int ntg = grp * 8 + ntl;
        *(half8*)(F + (((size_t)kc * 32 + ntg) * 64 + lane) * 8) = h;
    }
}

// ---- prep_ph: ph = hidden @ W2 + b1 + b2 via fp16 MFMA. M=16/block, 128 blocks. ----
__global__ __launch_bounds__(256) void prep_ph(const float* __restrict__ hidden,
                                               const unsigned short* __restrict__ F2,
                                               const float* __restrict__ b1,
                                               const float* __restrict__ b2,
                                               float* __restrict__ ph) {
    const int tid = threadIdx.x;
    const int w = tid >> 6;
    const int l = tid & 63;
    const int r0 = blockIdx.x * 16;

    floatx4 acc[8];
#pragma unroll
    for (int i = 0; i < 8; ++i) acc[i] = (floatx4){0.f, 0.f, 0.f, 0.f};

    const float* ap = hidden + (size_t)(r0 + (l & 15)) * UDIM + ((l >> 4) << 3);

    float4 a0 = *(const float4*)(ap);
    float4 a1 = *(const float4*)(ap + 4);
    half8 B[8];
#pragma unroll
    for (int nt = 0; nt < 8; ++nt) B[nt] = *bfrag(F2, 0, w * 8 + nt, l);

    for (int kc = 0; kc < 16; ++kc) {
        half8 a = cvt8(a0, a1);
        float4 n0, n1; half8 NB[8];
        if (kc < 15) {
            n0 = *(const float4*)(ap + (kc + 1) * 32);
            n1 = *(const float4*)(ap + (kc + 1) * 32 + 4);
#pragma unroll
            for (int nt = 0; nt < 8; ++nt) NB[nt] = *bfrag(F2, kc + 1, w * 8 + nt, l);
        }
#pragma unroll
        for (int nt = 0; nt < 8; ++nt)
            acc[nt] = __builtin_amdgcn_mfma_f32_16x16x32_f16(a, B[nt], acc[nt], 0, 0, 0);
        if (kc < 15) {
            a0 = n0; a1 = n1;
#pragma unroll
            for (int nt = 0; nt < 8; ++nt) B[nt] = NB[nt];
        }
    }
#pragma unroll
    for (int nt = 0; nt < 8; ++nt) {
        const int n = (w * 8 + nt) * 16 + (l & 15);
        const float bias = b1[n] + b2[n];
#pragma unroll
        for (int r = 0; r < 4; ++r) {
            const int m = (l >> 4) * 4 + r;
            ph[(size_t)(r0 + m) * UDIM + n] = acc[nt][r] + bias;
        }
    }
}

// ---- main: block = 1 batch (M=64), 512 threads / 8 waves, wave owns 64 cols.
// Whole A staged to LDS once (XOR-swizzled), ONE barrier, 8 kc barrier-free.
__global__ __launch_bounds__(512, 4) void attn_main(
    const float* __restrict__ feat, const unsigned short* __restrict__ F1,
    const float* __restrict__ ph, const float* __restrict__ Vw,
    const float* __restrict__ bv,
    float* __restrict__ ctx_out, float* __restrict__ w_out)
{
    __shared__ unsigned short lA[8 * 4 * 64 * 8];  // 32 KB: [kc][mt][lane^kc][8]
    __shared__ float phl[512];
    __shared__ float Vl[512];
    __shared__ float scp[8][64];
    __shared__ float wsm[64];
    __shared__ float ctxp[2][256];

    const int tid = threadIdx.x;
    const int w = tid >> 6;
    const int l = tid & 63;
    const size_t b = blockIdx.x;
    const float* fb = feat + b * (LDIM * EDIM);

    // ---- staging: 2 units/thread, 4 contiguous float4 each (deep MLP burst) ----
    // unit u: row r=u>>4, 16 cols at c0=(u&15)*16 -> kc=(u&15)>>1, octets (u&1)*2, +1
    float4 f4[2][4];
#pragma unroll
    for (int p = 0; p < 2; ++p) {
        const int u = tid + 512 * p;
        const float4* gp = (const float4*)(fb + (u >> 4) * EDIM + (u & 15) * 16);
        f4[p][0] = gp[0]; f4[p][1] = gp[1]; f4[p][2] = gp[2]; f4[p][3] = gp[3];
    }
    phl[tid] = ph[b * UDIM + tid];
    Vl[tid]  = Vw[tid];

#pragma unroll
    for (int p = 0; p < 2; ++p) {
        const int u  = tid + 512 * p;
        const int r  = u >> 4, kc = (u & 15) >> 1, o = (u & 1) * 2;
        const int mt = r >> 4, rr = r & 15;
        const int base = (kc * 4 + mt) * 64;
        *(half8*)&lA[(base + ((o * 16 + rr) ^ kc)) * 8]       = cvt8(f4[p][0], f4[p][1]);
        *(half8*)&lA[(base + (((o + 1) * 16 + rr) ^ kc)) * 8] = cvt8(f4[p][2], f4[p][3]);
    }

    floatx4 acc[4][4];  // [nt][mt]
#pragma unroll
    for (int i = 0; i < 4; ++i)
#pragma unroll
        for (int j = 0; j < 4; ++j) acc[i][j] = (floatx4){0.f, 0.f, 0.f, 0.f};

    __syncthreads();  // the ONE staging barrier

    // ---- GEMM: 8 kc, no barriers. B loads covered by TLP (16 waves/CU). ----
    for (int kc = 0; kc < 8; ++kc) {
        half8 Bc[4];
#pragma unroll
        for (int nt = 0; nt < 4; ++nt) Bc[nt] = *bfrag(F1, kc, w * 4 + nt, l);
        half8 a[4];
#pragma unroll
        for (int mt = 0; mt < 4; ++mt)
            a[mt] = *(const half8*)&lA[((kc * 4 + mt) * 64 + (l ^ kc)) * 8];
#pragma unroll
        for (int nt = 0; nt < 4; ++nt)
#pragma unroll
            for (int mt = 0; mt < 4; ++mt)
                acc[nt][mt] = __builtin_amdgcn_mfma_f32_16x16x32_f16(
                    a[mt], Bc[nt], acc[nt][mt], 0, 0, 0);
    }

    // ---- epilogue: tanh(acc + ph) * V -> per-row score partials ----
    float sv[4][4];
#pragma unroll
    for (int mt = 0; mt < 4; ++mt)
#pragma unroll
        for (int r = 0; r < 4; ++r) sv[mt][r] = 0.f;
#pragma unroll
    for (int nt = 0; nt < 4; ++nt) {
        const int n = (w * 4 + nt) * 16 + (l & 15);
        const float phn = phl[n];
        const float vn  = Vl[n];
#pragma unroll
        for (int mt = 0; mt < 4; ++mt)
#pragma unroll
            for (int r = 0; r < 4; ++r)
                sv[mt][r] += tanh_fast(acc[nt][mt][r] + phn) * vn;
    }
#pragma unroll
    for (int mt = 0; mt < 4; ++mt)
#pragma unroll
        for (int r = 0; r < 4; ++r) {
            float v = sv[mt][r];
            v += __shfl_xor(v, 1);
            v += __shfl_xor(v, 2);
            v += __shfl_xor(v, 4);
            v += __shfl_xor(v, 8);
            if ((l & 15) == 0) scp[w][mt * 16 + (l >> 4) * 4 + r] = v;
        }
    __syncthreads();

    // ---- softmax over L=64 (first 64 threads) ----
    if (tid < 64) {
        float s = bv[0];
#pragma unroll
        for (int wv = 0; wv < 8; ++wv) s += scp[wv][tid];
        float m = s;
        m = fmaxf(m, __shfl_xor(m, 32));
        m = fmaxf(m, __shfl_xor(m, 16));
        m = fmaxf(m, __shfl_xor(m, 8));
        m = fmaxf(m, __shfl_xor(m, 4));
        m = fmaxf(m, __shfl_xor(m, 2));
        m = fmaxf(m, __shfl_xor(m, 1));
        float e = __builtin_amdgcn_exp2f((s - m) * 1.44269504088896341f);
        float sum = e;
        sum += __shfl_xor(sum, 32);
        sum += __shfl_xor(sum, 16);
        sum += __shfl_xor(sum, 8);
        sum += __shfl_xor(sum, 4);
        sum += __shfl_xor(sum, 2);
        sum += __shfl_xor(sum, 1);
        float wgt = e / sum;
        wsm[tid] = wgt;
        w_out[b * LDIM + tid] = wgt;
    }
    __syncthreads();

    // ---- context: halves of rows per thread-group, then combine ----
    {
        const int e = tid & 255, h = tid >> 8;
        float c = 0.f;
#pragma unroll 8
        for (int ll = h * 32; ll < h * 32 + 32; ++ll)
            c = fmaf(wsm[ll], fb[ll * EDIM + e], c);
        ctxp[h][e] = c;
    }
    __syncthreads();
    if (tid < 256)
        ctx_out[b * EDIM + tid] = ctxp[0][tid] + ctxp[1][tid];
}

extern "C" void kernel_launch(void* const* d_in, const int* in_sizes, int n_in,
                              void* d_out, int out_size, void* d_ws, size_t ws_size,
                              hipStream_t stream) {
    const float* features = (const float*)d_in[0];
    const float* hidden   = (const float*)d_in[1];
    const float* W1       = (const float*)d_in[2];
    const float* b1       = (const float*)d_in[3];
    const float* W2       = (const float*)d_in[4];
    const float* b2       = (const float*)d_in[5];
    const float* Vw       = (const float*)d_in[6];
    const float* bv       = (const float*)d_in[7];

    float* ctx_out = (float*)d_out;
    float* w_out   = (float*)d_out + (size_t)BATCH * EDIM;

    float* ph = (float*)d_ws;
    unsigned short* F1 = (unsigned short*)(ph + (size_t)BATCH * UDIM);
    unsigned short* F2 = F1 + (size_t)8 * 32 * 64 * 8;

    prep_frag<<<dim3(96), dim3(256), 0, stream>>>(W1, W2, F1, F2);
    prep_ph<<<dim3(128), dim3(256), 0, stream>>>(hidden, F2, b1, b2, ph);
    attn_main<<<dim3(BATCH), dim3(512), 0, stream>>>(
        features, F1, ph, Vw, bv, ctx_out, w_out);
}